// Round 10
// baseline (4493.988 us; speedup 1.0000x reference)
//
#include <hip/hip_runtime.h>
#include <hip/hip_bf16.h>

typedef __attribute__((ext_vector_type(8))) short s8;
typedef __attribute__((ext_vector_type(4))) float f4;
typedef __attribute__((ext_vector_type(4))) unsigned int u4;

#define DEVI static __device__ __forceinline__

DEVI float bf2f(short u) {
  union { float f; unsigned int i; } v;
  v.i = ((unsigned int)(unsigned short)u) << 16;
  return v.f;
}
DEVI short f2bf(float f) {
  union { float f; unsigned int i; } v; v.f = f;
  unsigned int r = v.i + 0x7fffu + ((v.i >> 16) & 1u);
  return (short)(r >> 16);
}
DEVI void gload_lds16(const void* g, void* l) {
  __builtin_amdgcn_global_load_lds(
      (const __attribute__((address_space(1))) unsigned int*)g,
      (__attribute__((address_space(3))) unsigned int*)l, 16, 0, 0);
}
DEVI float sigm(float x) { return 1.f / (1.f + __expf(-x)); }

// sc0: bypass L1, serviced by the XCD's L2
DEVI u4 load4_sc0(const void* p) {
  u4 v;
  asm volatile("global_load_dwordx4 %0, %1, off sc0" : "=v"(v) : "v"(p) : "memory");
  return v;
}
// sc0 sc1: bypass L1+L2, serviced by IF$ (cross-XCD-safe)
DEVI u4 load4_sc01(const void* p) {
  u4 v;
  asm volatile("global_load_dwordx4 %0, %1, off sc0 sc1" : "=v"(v) : "v"(p) : "memory");
  return v;
}
DEVI unsigned int loadw_sc0(const unsigned int* p) {
  unsigned int v;
  asm volatile("global_load_dword %0, %1, off sc0" : "=v"(v) : "v"(p) : "memory");
  asm volatile("s_waitcnt vmcnt(0)" ::: "memory");
  return v;
}
DEVI unsigned int loadw_sc01(const unsigned int* p) {
  unsigned int v;
  asm volatile("global_load_dword %0, %1, off sc0 sc1" : "=v"(v) : "v"(p) : "memory");
  asm volatile("s_waitcnt vmcnt(0)" ::: "memory");
  return v;
}
DEVI void vm0_fence() {
  asm volatile("s_waitcnt vmcnt(0)" ::: "memory");
  __builtin_amdgcn_sched_barrier(0);
}

// LDS swizzle for hA [32 kc][16 row][64B]: XOR bits 4-5 with f(row>>1, kc).
// Bijective (mask independent of XORed bits); spreads lr and lr+4 across quads.
DEVI int hswz(int row, int kc) { return (((row >> 1) + kc) & 3) << 4; }

// ---------------- converts ----------------
// x [64][512][1024] f32  ->  xbf [512][64][1024] bf16 (t-major rows)
__global__ void k_x_relayout(const float* __restrict__ in, short* __restrict__ out) {
  long idx8 = (long)blockIdx.x * blockDim.x + threadIdx.x;
  long E = idx8 * 8;
  long row = E >> 10;
  long col = E & 1023;
  long t = row >> 6, b = row & 63;
  const float* src = in + ((b << 9) + t) * 1024 + col;
  float4 a = *(const float4*)(src);
  float4 c = *(const float4*)(src + 4);
  s8 o;
  o[0] = f2bf(a.x); o[1] = f2bf(a.y); o[2] = f2bf(a.z); o[3] = f2bf(a.w);
  o[4] = f2bf(c.x); o[5] = f2bf(c.y); o[6] = f2bf(c.z); o[7] = f2bf(c.w);
  *(s8*)(out + E) = o;
}

// src [1024][1024] f32 row-major [k][n]  ->  dst [1024][1024] bf16 at [n][k]
__global__ void k_transpose_c(const float* __restrict__ src, short* __restrict__ dst) {
  __shared__ float tile[32][33];
  int n0 = blockIdx.x * 32, k0 = blockIdx.y * 32;
  int lx = threadIdx.x & 31, ly = threadIdx.x >> 5;
#pragma unroll
  for (int r = 0; r < 32; r += 8)
    tile[ly + r][lx] = src[(long)(k0 + ly + r) * 1024 + n0 + lx];
  __syncthreads();
#pragma unroll
  for (int r = 0; r < 32; r += 8)
    dst[(long)(n0 + ly + r) * 1024 + k0 + lx] = f2bf(tile[lx][ly + r]);
}

__global__ void k_bcat(const float* __restrict__ b0, const float* __restrict__ b1,
                       const float* __restrict__ b2, const float* __restrict__ b3,
                       float* __restrict__ o) {
  int i = blockIdx.x * 256 + threadIdx.x;
  int j = i & 1023;
  float v;
  switch (i >> 10) { case 0: v = b0[j]; break; case 1: v = b1[j]; break;
                     case 2: v = b2[j]; break; default: v = b3[j]; }
  o[i] = v;
}

// ---------------- bf16 GEMM: C[M][N] = A[M][K] @ Bt[N][K]^T + bias ----------------
// REMAP 0: linear. 1: row (t*64+b) -> (b*512+t).
// REMAP 2: XG permute [t][rb8][ug32][g4][row8][u32] for the recurrence kernel.
template <typename OutT, int REMAP>
__global__ __launch_bounds__(256) void k_gemm_bt(
    const short* __restrict__ A, const short* __restrict__ Bt,
    const float* __restrict__ bias, OutT* __restrict__ C,
    int M, int N, int K) {
  __shared__ __align__(16) char As[8192];
  __shared__ __align__(16) char Bs[8192];
  const int tid = threadIdx.x;
  const int wid = tid >> 6, lane = tid & 63;
  const int lr = lane & 15, lk = lane >> 4;
  const int wy = wid >> 1, wx = wid & 1;
  const long bm = (long)blockIdx.y * 128, bn = (long)blockIdx.x * 128;
  const char* Ab = (const char*)A;
  const char* Bb = (const char*)Bt;
  f4 acc[4][4];
#pragma unroll
  for (int i = 0; i < 4; ++i)
#pragma unroll
    for (int j = 0; j < 4; ++j) acc[i][j] = f4{0.f, 0.f, 0.f, 0.f};

  for (int k0 = 0; k0 < K; k0 += 32) {
#pragma unroll
    for (int p = 0; p < 2; ++p) {
      int off = p * 4096 + tid * 16;
      int r = off >> 6, cb = off & 63;
      int sw = cb ^ ((r & 3) << 4);
      gload_lds16(Ab + ((bm + r) * K + k0) * 2 + sw, As + p * 4096 + wid * 1024);
      gload_lds16(Bb + ((bn + r) * K + k0) * 2 + sw, Bs + p * 4096 + wid * 1024);
    }
    __syncthreads();
    s8 af[4], bfr[4];
#pragma unroll
    for (int mi = 0; mi < 4; ++mi) {
      int r = wy * 64 + mi * 16 + lr;
      int x = r * 64 + lk * 16;
      af[mi] = *(const s8*)(As + (x ^ ((r & 3) << 4)));
    }
#pragma unroll
    for (int ni = 0; ni < 4; ++ni) {
      int r = wx * 64 + ni * 16 + lr;
      int x = r * 64 + lk * 16;
      bfr[ni] = *(const s8*)(Bs + (x ^ ((r & 3) << 4)));
    }
#pragma unroll
    for (int mi = 0; mi < 4; ++mi)
#pragma unroll
      for (int ni = 0; ni < 4; ++ni)
        acc[mi][ni] = __builtin_amdgcn_mfma_f32_16x16x32_bf16(af[mi], bfr[ni], acc[mi][ni], 0, 0, 0);
    __syncthreads();
  }
#pragma unroll
  for (int mi = 0; mi < 4; ++mi)
#pragma unroll
    for (int ni = 0; ni < 4; ++ni)
#pragma unroll
      for (int j = 0; j < 4; ++j) {
        long row = bm + wy * 64 + mi * 16 + lk * 4 + j;
        long col = bn + wx * 64 + ni * 16 + lr;
        float v = acc[mi][ni][j] + bias[col];
        long off;
        if constexpr (REMAP == 1) {
          off = ((row & 63) * 512 + (row >> 6)) * (long)N + col;
        } else if constexpr (REMAP == 2) {
          long tt = row >> 6, b = row & 63;
          long gg = col >> 10, u = col & 1023;
          off = (((((tt << 3) + (b >> 3)) << 5) + (u >> 5)) * 4 + gg) * 256 +
                ((b & 7) << 5) + (u & 31);
        } else {
          off = row * (long)N + col;
        }
        if constexpr (sizeof(OutT) == 2) C[off] = f2bf(v);
        else                              C[off] = v;
      }
}

// ---------------- persistent LSTM recurrence (per-wave flags, 2 barriers/step) ----
// 256 WGs x 512 threads, 1 WG/CU. WG = (rb = wg&7: 8 batch rows) x (ug = wg>>3: 32 units).
// Per-wave protocol: elementwise waves 0-3 each own 2 rows; each publishes its h
// (plain -> local L2), drains ITS OWN vmcnt, raises ITS OWN flag (4 flags/WG).
// Staging wave srow polls only the 32 flags of elem-wave (srow>>1) -- the exact
// producers of its row. No whole-WG convergence on publish or poll; only 2
// __syncthreads per step (hA-ready, pre-ready). hA overwrite for t+1 is safe:
// flags(t+1) imply elementwise(t) done, which is post-S3, so all MFMA(t) reads done.
// Recovery (cross-XCD mapping): sticky eflag; on 4096-round timeout, elem waves
// republish hP0/hP1 + flag at agent scope (IF$), polls/bulk switch to sc0+sc1.
__global__ __launch_bounds__(512, 2) void k_lstm_p(
    const short* __restrict__ XG,     // [512][8][32][4][8][32] permuted, bias folded
    const short* __restrict__ Wht,    // [4096][1024]
    short* __restrict__ hbuf,         // [2][64][1024] bf16
    unsigned int* __restrict__ flags, // [256 WG][4 waves] spaced 16 u32 (64 B)
    short* __restrict__ HS) {         // [512][64][1024] bf16
  __shared__ __align__(16) char hA[32768];   // [32 kc][16 row][64B], swz = hswz()
  __shared__ float pre[2][4][8][33];          // [kh][gate][row][unit]
  __shared__ int eflag;                       // sticky: 1 => escalated (IF$ mode)

  const int tid = threadIdx.x;
  const int wg = blockIdx.x;
  const int wid = tid >> 6, lane = tid & 63;
  const int lr = lane & 15, lk = lane >> 4;
  const int g = wid & 3, kh = wid >> 2;
  const int rb = wg & 7, ug = wg >> 3;

  if (tid == 0) eflag = 0;

  // recurrent-weight B-fragments: [nt(2)][kc(16)] = 32 x s8 (unified VGPR/AGPR file)
  s8 wf[32];
  {
    const short* wbase = Wht + (long)(g * 1024 + ug * 32 + lr) * 1024 + kh * 512 + lk * 8;
#pragma unroll
    for (int nt = 0; nt < 2; ++nt)
#pragma unroll
      for (int kc = 0; kc < 16; ++kc)
        wf[nt * 16 + kc] = *(const s8*)(wbase + nt * 16384 + kc * 32);
  }
#pragma unroll
  for (int i = 0; i < 32; ++i) asm volatile("" : "+v"(wf[i]));

  const int srow = wid;               // staging row 0..7 (= wave id)
  const int ew = srow >> 1;           // producing elementwise wave of this row
  // zero pad rows 8..15 of hA once (MFMA M=16, only 8 real rows)
  {
    int zr = 8 + srow;
    int kc = lane >> 1;
    int base = kc * 1024 + zr * 64 + (lane & 1) * 32;
    int sw = hswz(zr, kc);
    *(u4*)(hA + (base ^ sw)) = u4{0, 0, 0, 0};
    *(u4*)(hA + ((base + 16) ^ sw)) = u4{0, 0, 0, 0};
  }

  const int erow = (tid >> 5) & 7, eu = tid & 31;  // elementwise ids (valid wid<4)
  const int grow = rb * 8 + erow;
  const int gu = ug * 32 + eu;
  float c = 0.f;
  short hP0 = 0, hP1 = 0;   // last published h per parity (recovery republish)

  // h0 = 0 (parity-0, plain) + per-wave flag = 1 (plain + agent once)
  if (wid < 4) {
    short* p = &hbuf[(long)grow * 1024 + gu];
    *(volatile short*)p = 0;
    vm0_fence();
    if (lane == 0) {
      unsigned int* mf = &flags[(unsigned)(((rb << 5) + ug) * 4 + wid) << 4];
      *(volatile unsigned int*)mf = 1u;
      __hip_atomic_store(mf, 1u, __ATOMIC_RELAXED, __HIP_MEMORY_SCOPE_AGENT);
    }
  }
  __syncthreads();  // eflag + hA pad visible

  // XG prefetch for t=0 into xE
  short xE[4], xO[4];
  if (wid < 4) {
    const short* ep = XG + (long)((0 * 8 + rb) * 32 + ug) * 1024 + erow * 32 + eu;
    xE[0] = ep[0]; xE[1] = ep[256]; xE[2] = ep[512]; xE[3] = ep[768];
  }

#define LSTM_STEP(T, XA, XB)                                                    \
  {                                                                             \
    const int t_ = (T);                                                         \
    const unsigned int target = (unsigned int)(t_ + 1);                         \
    { /* per-wave poll of the 32 producers of row srow */                       \
      const unsigned int* fp =                                                  \
          &flags[(unsigned)(((rb << 5) + (lane & 31)) * 4 + ew) << 4];          \
      int esc = *(volatile int*)&eflag;                                         \
      int rounds = 0;                                                           \
      while (true) {                                                            \
        unsigned int v = esc ? loadw_sc01(fp) : loadw_sc0(fp);                  \
        if (__all((int)(v >= target))) break;                                   \
        ++rounds;                                                               \
        if (rounds >= 4096 && (rounds & 4095) == 0) {                           \
          if (lane == 0) eflag = 1;                                             \
          esc = 1;                                                              \
          if (wid < 4) { /* republish own rows + flag at IF$ */                 \
            __hip_atomic_store(&hbuf[(long)grow * 1024 + gu], hP0,              \
                               __ATOMIC_RELAXED, __HIP_MEMORY_SCOPE_AGENT);     \
            __hip_atomic_store(&hbuf[65536 + (long)grow * 1024 + gu], hP1,      \
                               __ATOMIC_RELAXED, __HIP_MEMORY_SCOPE_AGENT);     \
            vm0_fence();                                                        \
            if (lane == 0) {                                                    \
              unsigned int* mf =                                                \
                  &flags[(unsigned)(((rb << 5) + ug) * 4 + wid) << 4];          \
              __hip_atomic_store(mf, target, __ATOMIC_RELAXED,                  \
                                 __HIP_MEMORY_SCOPE_AGENT);                     \
            }                                                                   \
          }                                                                     \
        } else {                                                                \
          esc = *(volatile int*)&eflag;                                         \
        }                                                                       \
        if (rounds > (1 << 20)) break;                                          \
      }                                                                         \
    }                                                                           \
    const int esc_ = *(volatile int*)&eflag;                                    \
    { /* bulk-stage own row (2KB via 64 lanes x 32B), once */                   \
      const char* rowp = (const char*)(hbuf + (t_ & 1) * 65536 +                \
                                       (long)(rb * 8 + srow) * 1024) +          \
                         lane * 32;                                             \
      u4 v0, v1;                                                                \
      if (esc_) { v0 = load4_sc01(rowp); v1 = load4_sc01(rowp + 16); }          \
      else      { v0 = load4_sc0(rowp);  v1 = load4_sc0(rowp + 16); }           \
      vm0_fence();                                                              \
      int kc_ = lane >> 1;                                                      \
      int wb = kc_ * 1024 + srow * 64 + (lane & 1) * 32;                        \
      int sw = hswz(srow, kc_);                                                 \
      *(u4*)(hA + (wb ^ sw)) = v0;                                              \
      *(u4*)(hA + ((wb + 16) ^ sw)) = v1;                                       \
    }                                                                           \
    __syncthreads(); /* S2: hA ready */                                         \
    f4 a0{0.f, 0.f, 0.f, 0.f}, a1{0.f, 0.f, 0.f, 0.f};                          \
    _Pragma("unroll")                                                           \
    for (int kc2 = 0; kc2 < 16; ++kc2) {                                        \
      int kci = kh * 16 + kc2;                                                  \
      int ad = (kci * 1024 + lr * 64 + lk * 16) ^ hswz(lr, kci);                \
      s8 ah = *(const s8*)(hA + ad);                                            \
      a0 = __builtin_amdgcn_mfma_f32_16x16x32_bf16(ah, wf[kc2], a0, 0, 0, 0);   \
      a1 = __builtin_amdgcn_mfma_f32_16x16x32_bf16(ah, wf[16 + kc2], a1, 0, 0, 0); \
    }                                                                           \
    if (lk < 2) {                                                               \
      _Pragma("unroll")                                                         \
      for (int j = 0; j < 4; ++j) {                                             \
        pre[kh][g][lk * 4 + j][lr] = a0[j];                                     \
        pre[kh][g][lk * 4 + j][16 + lr] = a1[j];                                \
      }                                                                         \
    }                                                                           \
    __syncthreads(); /* S3: pre ready */                                        \
    if (wid < 4) {                                                              \
      float pi = pre[0][0][erow][eu] + pre[1][0][erow][eu] + bf2f(XA[0]);       \
      float pf = pre[0][1][erow][eu] + pre[1][1][erow][eu] + bf2f(XA[1]);       \
      float po = pre[0][2][erow][eu] + pre[1][2][erow][eu] + bf2f(XA[2]);       \
      float pc = pre[0][3][erow][eu] + pre[1][3][erow][eu] + bf2f(XA[3]);       \
      float fi = sigm(pi), ff = sigm(pf), fo = sigm(po);                        \
      float ch = tanhf(pc);                                                     \
      c = ff * c + fi * ch;                                                     \
      float h = fo * tanhf(c);                                                  \
      short hh = f2bf(h);                                                       \
      short* p = &hbuf[((t_ + 1) & 1) * 65536 + (long)grow * 1024 + gu];        \
      *(volatile short*)p = hh;                                                 \
      if (esc_)                                                                 \
        __hip_atomic_store(p, hh, __ATOMIC_RELAXED, __HIP_MEMORY_SCOPE_AGENT);  \
      if ((t_ + 1) & 1) hP1 = hh; else hP0 = hh;                                \
      vm0_fence(); /* per-wave: own h stores ack'd at L2 */                     \
      if (lane == 0) {                                                          \
        unsigned int* mf = &flags[(unsigned)(((rb << 5) + ug) * 4 + wid) << 4]; \
        *(volatile unsigned int*)mf = (unsigned int)(t_ + 2);                   \
        if (esc_)                                                               \
          __hip_atomic_store(mf, (unsigned int)(t_ + 2), __ATOMIC_RELAXED,      \
                             __HIP_MEMORY_SCOPE_AGENT);                         \
      }                                                                         \
      HS[(long)t_ * 65536 + (long)grow * 1024 + gu] = hh;                       \
      { /* XG prefetch t+1 into XB (post-flag: drains in next bulk fence) */    \
        int tn = (t_ + 1) & 511;                                                \
        const short* ep = XG + (long)((tn * 8 + rb) * 32 + ug) * 1024 +         \
                          erow * 32 + eu;                                       \
        XB[0] = ep[0]; XB[1] = ep[256]; XB[2] = ep[512]; XB[3] = ep[768];       \
      }                                                                         \
    }                                                                           \
  }

  for (int t2 = 0; t2 < 512; t2 += 2) {
    LSTM_STEP(t2, xE, xO);
    LSTM_STEP(t2 + 1, xO, xE);
  }
#undef LSTM_STEP
}

// ---------------- launch ----------------
extern "C" void kernel_launch(void* const* d_in, const int* in_sizes, int n_in,
                              void* d_out, int out_size, void* d_ws, size_t ws_size,
                              hipStream_t stream) {
  const float* x = (const float*)d_in[0];
  const float* Wx[4] = {(const float*)d_in[1], (const float*)d_in[4], (const float*)d_in[7], (const float*)d_in[10]};
  const float* Wh[4] = {(const float*)d_in[2], (const float*)d_in[5], (const float*)d_in[8], (const float*)d_in[11]};
  const float* bg[4] = {(const float*)d_in[3], (const float*)d_in[6], (const float*)d_in[9], (const float*)d_in[12]};
  const float* Why = (const float*)d_in[13];
  const float* by  = (const float*)d_in[14];

  char* ws = (char*)d_ws;                     // layout (bytes):
  short* xbf  = (short*)(ws);                 // 67,108,864  x bf16 [512][64][1024]
  short* HS   = (short*)(ws);                 // reuses xbf (dead after big GEMM)
  short* Wxt  = (short*)(ws + 67108864);      //  8,388,608
  short* Wht  = (short*)(ws + 75497472);      //  8,388,608
  short* Whyt = (short*)(ws + 83886080);      //  2,097,152
  float* bcat = (float*)(ws + 85983232);      //     16,384
  short* XG   = (short*)(ws + 85999616);      // 268,435,456 [512][8][32][4][8][32]
  short* hbuf = (short*)(ws + 354435072);     //    262,144  [2][64][1024] bf16
  unsigned int* flags = (unsigned int*)(ws + 354697216);  // 65,536 (1024 x 64B)

  hipLaunchKernelGGL(k_x_relayout, dim3(16384), dim3(256), 0, stream, x, xbf);
  for (int gi = 0; gi < 4; ++gi) {
    hipLaunchKernelGGL(k_transpose_c, dim3(32, 32), dim3(256), 0, stream, Wx[gi], Wxt + (long)gi * 1048576);
    hipLaunchKernelGGL(k_transpose_c, dim3(32, 32), dim3(256), 0, stream, Wh[gi], Wht + (long)gi * 1048576);
  }
  hipLaunchKernelGGL(k_transpose_c, dim3(32, 32), dim3(256), 0, stream, Why, Whyt);
  hipLaunchKernelGGL(k_bcat, dim3(16), dim3(256), 0, stream, bg[0], bg[1], bg[2], bg[3], bcat);

  hipLaunchKernelGGL((k_gemm_bt<short, 2>), dim3(32, 256), dim3(256), 0, stream,
                     xbf, Wxt, bcat, XG, 32768, 4096, 1024);

  hipMemsetAsync(flags, 0, 65536, stream);

  {
    void* args[] = { (void*)&XG, (void*)&Wht, (void*)&hbuf, (void*)&flags, (void*)&HS };
    hipLaunchCooperativeKernel((void*)k_lstm_p, dim3(256), dim3(512), args, 0, stream);
  }

  hipLaunchKernelGGL((k_gemm_bt<float, 1>), dim3(8, 256), dim3(256), 0, stream,
                     HS, Whyt, by, (float*)d_out, 32768, 1024, 1024);
}

// Round 11
// 3008.262 us; speedup vs baseline: 1.4939x; 1.4939x over previous
//
#include <hip/hip_runtime.h>
#include <hip/hip_bf16.h>

typedef __attribute__((ext_vector_type(8))) short s8;
typedef __attribute__((ext_vector_type(4))) float f4;
typedef __attribute__((ext_vector_type(4))) unsigned int u4;

#define DEVI static __device__ __forceinline__

DEVI float bf2f(short u) {
  union { float f; unsigned int i; } v;
  v.i = ((unsigned int)(unsigned short)u) << 16;
  return v.f;
}
DEVI float bf2fu(unsigned int u) {
  union { float f; unsigned int i; } v;
  v.i = u << 16;
  return v.f;
}
DEVI short f2bf(float f) {
  union { float f; unsigned int i; } v; v.f = f;
  unsigned int r = v.i + 0x7fffu + ((v.i >> 16) & 1u);
  return (short)(r >> 16);
}
DEVI void gload_lds16(const void* g, void* l) {
  __builtin_amdgcn_global_load_lds(
      (const __attribute__((address_space(1))) unsigned int*)g,
      (__attribute__((address_space(3))) unsigned int*)l, 16, 0, 0);
}
DEVI float sigm(float x) { return 1.f / (1.f + __expf(-x)); }
// fast tanh: 1 - 2/(e^2x + 1); saturates to +-1 cleanly (e->inf or 0)
DEVI float tanh_f(float x) { return 1.f - 2.f / (__expf(2.f * x) + 1.f); }

// sc0: bypass L1, serviced by the XCD's L2
DEVI u4 load4_sc0(const void* p) {
  u4 v;
  asm volatile("global_load_dwordx4 %0, %1, off sc0" : "=v"(v) : "v"(p) : "memory");
  return v;
}
// sc0 sc1: bypass L1+L2, serviced by IF$ (cross-XCD-safe)
DEVI u4 load4_sc01(const void* p) {
  u4 v;
  asm volatile("global_load_dwordx4 %0, %1, off sc0 sc1" : "=v"(v) : "v"(p) : "memory");
  return v;
}
DEVI unsigned int loadw_sc0(const unsigned int* p) {
  unsigned int v;
  asm volatile("global_load_dword %0, %1, off sc0" : "=v"(v) : "v"(p) : "memory");
  asm volatile("s_waitcnt vmcnt(0)" ::: "memory");
  return v;
}
DEVI unsigned int loadw_sc01(const unsigned int* p) {
  unsigned int v;
  asm volatile("global_load_dword %0, %1, off sc0 sc1" : "=v"(v) : "v"(p) : "memory");
  asm volatile("s_waitcnt vmcnt(0)" ::: "memory");
  return v;
}
// ushort load, no wait (counted-vmcnt region)
DEVI unsigned int loadus_nw(const void* p) {
  unsigned int v;
  asm volatile("global_load_ushort %0, %1, off" : "=v"(v) : "v"(p) : "memory");
  return v;
}
DEVI void vm0_fence() {
  asm volatile("s_waitcnt vmcnt(0)" ::: "memory");
  __builtin_amdgcn_sched_barrier(0);
}

// LDS swizzle for hA [32 kc][16 row][64B]: XOR bits 4-5 with f(row>>1, kc).
// Bijective (mask independent of XORed bits); spreads lr and lr+4 across quads.
DEVI int hswz(int row, int kc) { return (((row >> 1) + kc) & 3) << 4; }

// ---------------- converts ----------------
// x [64][512][1024] f32  ->  xbf [512][64][1024] bf16 (t-major rows)
__global__ void k_x_relayout(const float* __restrict__ in, short* __restrict__ out) {
  long idx8 = (long)blockIdx.x * blockDim.x + threadIdx.x;
  long E = idx8 * 8;
  long row = E >> 10;
  long col = E & 1023;
  long t = row >> 6, b = row & 63;
  const float* src = in + ((b << 9) + t) * 1024 + col;
  float4 a = *(const float4*)(src);
  float4 c = *(const float4*)(src + 4);
  s8 o;
  o[0] = f2bf(a.x); o[1] = f2bf(a.y); o[2] = f2bf(a.z); o[3] = f2bf(a.w);
  o[4] = f2bf(c.x); o[5] = f2bf(c.y); o[6] = f2bf(c.z); o[7] = f2bf(c.w);
  *(s8*)(out + E) = o;
}

// src [1024][1024] f32 row-major [k][n]  ->  dst [1024][1024] bf16 at [n][k]
__global__ void k_transpose_c(const float* __restrict__ src, short* __restrict__ dst) {
  __shared__ float tile[32][33];
  int n0 = blockIdx.x * 32, k0 = blockIdx.y * 32;
  int lx = threadIdx.x & 31, ly = threadIdx.x >> 5;
#pragma unroll
  for (int r = 0; r < 32; r += 8)
    tile[ly + r][lx] = src[(long)(k0 + ly + r) * 1024 + n0 + lx];
  __syncthreads();
#pragma unroll
  for (int r = 0; r < 32; r += 8)
    dst[(long)(n0 + ly + r) * 1024 + k0 + lx] = f2bf(tile[lx][ly + r]);
}

__global__ void k_bcat(const float* __restrict__ b0, const float* __restrict__ b1,
                       const float* __restrict__ b2, const float* __restrict__ b3,
                       float* __restrict__ o) {
  int i = blockIdx.x * 256 + threadIdx.x;
  int j = i & 1023;
  float v;
  switch (i >> 10) { case 0: v = b0[j]; break; case 1: v = b1[j]; break;
                     case 2: v = b2[j]; break; default: v = b3[j]; }
  o[i] = v;
}

// ---------------- bf16 GEMM: C[M][N] = A[M][K] @ Bt[N][K]^T + bias ----------------
// REMAP 0: linear. 1: row (t*64+b) -> (b*512+t).
// REMAP 2: XG permute [t][rb8][ug32][g4][row8][u32] for the recurrence kernel.
template <typename OutT, int REMAP>
__global__ __launch_bounds__(256) void k_gemm_bt(
    const short* __restrict__ A, const short* __restrict__ Bt,
    const float* __restrict__ bias, OutT* __restrict__ C,
    int M, int N, int K) {
  __shared__ __align__(16) char As[8192];
  __shared__ __align__(16) char Bs[8192];
  const int tid = threadIdx.x;
  const int wid = tid >> 6, lane = tid & 63;
  const int lr = lane & 15, lk = lane >> 4;
  const int wy = wid >> 1, wx = wid & 1;
  const long bm = (long)blockIdx.y * 128, bn = (long)blockIdx.x * 128;
  const char* Ab = (const char*)A;
  const char* Bb = (const char*)Bt;
  f4 acc[4][4];
#pragma unroll
  for (int i = 0; i < 4; ++i)
#pragma unroll
    for (int j = 0; j < 4; ++j) acc[i][j] = f4{0.f, 0.f, 0.f, 0.f};

  for (int k0 = 0; k0 < K; k0 += 32) {
#pragma unroll
    for (int p = 0; p < 2; ++p) {
      int off = p * 4096 + tid * 16;
      int r = off >> 6, cb = off & 63;
      int sw = cb ^ ((r & 3) << 4);
      gload_lds16(Ab + ((bm + r) * K + k0) * 2 + sw, As + p * 4096 + wid * 1024);
      gload_lds16(Bb + ((bn + r) * K + k0) * 2 + sw, Bs + p * 4096 + wid * 1024);
    }
    __syncthreads();
    s8 af[4], bfr[4];
#pragma unroll
    for (int mi = 0; mi < 4; ++mi) {
      int r = wy * 64 + mi * 16 + lr;
      int x = r * 64 + lk * 16;
      af[mi] = *(const s8*)(As + (x ^ ((r & 3) << 4)));
    }
#pragma unroll
    for (int ni = 0; ni < 4; ++ni) {
      int r = wx * 64 + ni * 16 + lr;
      int x = r * 64 + lk * 16;
      bfr[ni] = *(const s8*)(Bs + (x ^ ((r & 3) << 4)));
    }
#pragma unroll
    for (int mi = 0; mi < 4; ++mi)
#pragma unroll
      for (int ni = 0; ni < 4; ++ni)
        acc[mi][ni] = __builtin_amdgcn_mfma_f32_16x16x32_bf16(af[mi], bfr[ni], acc[mi][ni], 0, 0, 0);
    __syncthreads();
  }
#pragma unroll
  for (int mi = 0; mi < 4; ++mi)
#pragma unroll
    for (int ni = 0; ni < 4; ++ni)
#pragma unroll
      for (int j = 0; j < 4; ++j) {
        long row = bm + wy * 64 + mi * 16 + lk * 4 + j;
        long col = bn + wx * 64 + ni * 16 + lr;
        float v = acc[mi][ni][j] + bias[col];
        long off;
        if constexpr (REMAP == 1) {
          off = ((row & 63) * 512 + (row >> 6)) * (long)N + col;
        } else if constexpr (REMAP == 2) {
          long tt = row >> 6, b = row & 63;
          long gg = col >> 10, u = col & 1023;
          off = (((((tt << 3) + (b >> 3)) << 5) + (u >> 5)) * 4 + gg) * 256 +
                ((b & 7) << 5) + (u & 31);
        } else {
          off = row * (long)N + col;
        }
        if constexpr (sizeof(OutT) == 2) C[off] = f2bf(v);
        else                              C[off] = v;
      }
}

// ---------------- persistent LSTM recurrence (R9 protocol + poller wave) --------
// 256 WGs x 512 threads, 1 WG/CU. WG = (rb = wg&7: 8 batch rows) x (ug = wg>>3: 32 units).
// ONE flag per WG (R9 semantics). Wave 4 is the dedicated poller: polls the 32
// producer flags of rb (sc0, 128 B/round), then broadcasts via LDS `pollok`.
// Elementwise waves (0-3) publish h (plain -> local L2), drain OWN vmcnt, and
// LDS-atomic count; the 4th wave raises the WG flag. 2 __syncthreads per step.
// Counted vmcnt in the stage phase keeps the XG (HBM) prefetch OFF the critical
// chain: wait vmcnt(4) passes once the two L2 h-loads land.
// Recovery (cross-XCD mapping): poller sets sticky eflag during the stall;
// spinning elementwise waves republish both h parities at agent scope, ordered
// by an LDS recovery counter before the flag republish; everything then runs
// dual-scope (plain+agent, sc0+sc1). Wrong mapping costs a transient, never
// correctness; bounded guards fail visibly instead of hanging.
__global__ __launch_bounds__(512, 2) void k_lstm_p(
    const short* __restrict__ XG,     // [512][8][32][4][8][32] permuted, bias folded
    const short* __restrict__ Wht,    // [4096][1024]
    short* __restrict__ hbuf,         // [2][64][1024] bf16
    unsigned int* __restrict__ flags, // [256] monotonic, spaced 16 u32 (64 B)
    short* __restrict__ HS) {         // [512][64][1024] bf16
  __shared__ __align__(16) char hA[32768];   // [32 kc][16 row][64B], swz = hswz()
  __shared__ float pre[2][4][8][33];          // [kh][gate][row][unit]
  __shared__ int eflag;                       // sticky: 1 => escalated (IF$ mode)
  __shared__ int pollok;                      // highest confirmed poll target
  __shared__ unsigned int cnt;                // monotonic publish counter (4/step)
  __shared__ unsigned int rcnt;               // recovery republish counter

  const int tid = threadIdx.x;
  const int wg = blockIdx.x;
  const int wid = tid >> 6, lane = tid & 63;
  const int lr = lane & 15, lk = lane >> 4;
  const int g = wid & 3, kh = wid >> 2;
  const int rb = wg & 7, ug = wg >> 3;

  if (tid == 0) { eflag = 0; pollok = 0; cnt = 0; rcnt = 0; }

  // recurrent-weight B-fragments: [nt(2)][kc(16)] = 32 x s8 (unified VGPR/AGPR file)
  s8 wf[32];
  {
    const short* wbase = Wht + (long)(g * 1024 + ug * 32 + lr) * 1024 + kh * 512 + lk * 8;
#pragma unroll
    for (int nt = 0; nt < 2; ++nt)
#pragma unroll
      for (int kc = 0; kc < 16; ++kc)
        wf[nt * 16 + kc] = *(const s8*)(wbase + nt * 16384 + kc * 32);
  }
#pragma unroll
  for (int i = 0; i < 32; ++i) asm volatile("" : "+v"(wf[i]));

  const int srow = wid;               // staging row 0..7 (= wave id)
  // zero pad rows 8..15 of hA once (MFMA M=16, only 8 real rows)
  {
    int zr = 8 + srow;
    int kc = lane >> 1;
    int base = kc * 1024 + zr * 64 + (lane & 1) * 32;
    int sw = hswz(zr, kc);
    *(u4*)(hA + (base ^ sw)) = u4{0, 0, 0, 0};
    *(u4*)(hA + ((base + 16) ^ sw)) = u4{0, 0, 0, 0};
  }

  const int erow = (tid >> 5) & 7, eu = tid & 31;  // elementwise ids (valid wid<4)
  const int grow = rb * 8 + erow;
  const int gu = ug * 32 + eu;
  float c = 0.f;
  short hP0 = 0, hP1 = 0;   // last published h per parity (recovery republish)
  unsigned int* const myflag = &flags[(unsigned)((rb << 5) + ug) << 4];

  __syncthreads();  // LDS init + pad visible

  // h0 = 0 (parity-0, plain); per-wave fence; 4th wave raises flag = 1
  if (wid < 4) {
    short* p = &hbuf[(long)grow * 1024 + gu];
    *(volatile short*)p = 0;
    vm0_fence();
    if (lane == 0) {
      unsigned int old = atomicAdd(&cnt, 1u);
      if (old == 3u) {
        *(volatile unsigned int*)myflag = 1u;
        __hip_atomic_store(myflag, 1u, __ATOMIC_RELAXED, __HIP_MEMORY_SCOPE_AGENT);
      }
    }
  }

  // XG prefetch for t=0
  unsigned int xE[4], xO[4];
  if (wid < 4) {
    const short* ep = XG + (long)((0 * 8 + rb) * 32 + ug) * 1024 + erow * 32 + eu;
    xE[0] = loadus_nw(ep); xE[1] = loadus_nw(ep + 256);
    xE[2] = loadus_nw(ep + 512); xE[3] = loadus_nw(ep + 768);
    vm0_fence();
  }

#define LSTM_STEP(T, XA, XB)                                                    \
  {                                                                             \
    const int t_ = (T);                                                         \
    const unsigned int target = (unsigned int)(t_ + 1);                         \
    if (wid == 4) { /* dedicated poller */                                      \
      int esc = *(volatile int*)&eflag;                                         \
      if (lane < 32) {                                                          \
        const unsigned int* f = &flags[(unsigned)((rb << 5) + lane) << 4];      \
        int rounds = 0;                                                         \
        while (true) {                                                          \
          unsigned int v = esc ? loadw_sc01(f) : loadw_sc0(f);                  \
          if (v >= target) break;                                               \
          ++rounds;                                                             \
          if (rounds == 2048) { *(volatile int*)&eflag = 1; esc = 1; }          \
          if (rounds > (1 << 20)) break;                                        \
        }                                                                       \
      }                                                                         \
      if (lane == 0) *(volatile int*)&pollok = (int)target;                     \
    } else { /* spin on LDS broadcast; republish if escalated */                \
      int repub = 0, guard = 0;                                                 \
      while (*(volatile int*)&pollok < (int)target) {                           \
        if (!repub && *(volatile int*)&eflag) {                                 \
          if (wid < 4) {                                                        \
            __hip_atomic_store(&hbuf[(long)grow * 1024 + gu], hP0,              \
                               __ATOMIC_RELAXED, __HIP_MEMORY_SCOPE_AGENT);     \
            __hip_atomic_store(&hbuf[65536 + (long)grow * 1024 + gu], hP1,      \
                               __ATOMIC_RELAXED, __HIP_MEMORY_SCOPE_AGENT);     \
            vm0_fence();                                                        \
            if (lane == 0) {                                                    \
              unsigned int old = atomicAdd(&rcnt, 1u);                          \
              if (old == 3u)                                                    \
                __hip_atomic_store(myflag, target, __ATOMIC_RELAXED,            \
                                   __HIP_MEMORY_SCOPE_AGENT);                   \
            }                                                                   \
          }                                                                     \
          repub = 1;                                                            \
        }                                                                       \
        __builtin_amdgcn_s_sleep(1);                                            \
        if (++guard > (1 << 22)) break;                                         \
      }                                                                         \
    }                                                                           \
    const int esc_ = *(volatile int*)&eflag;                                    \
    { /* stage own row; counted vmcnt keeps XG off the critical chain */        \
      const char* rowp = (const char*)(hbuf + (t_ & 1) * 65536 +                \
                                       (long)(rb * 8 + srow) * 1024) +          \
                         lane * 32;                                             \
      u4 v0, v1;                                                                \
      if (esc_) { v0 = load4_sc01(rowp); v1 = load4_sc01(rowp + 16); }          \
      else      { v0 = load4_sc0(rowp);  v1 = load4_sc0(rowp + 16); }           \
      if (wid < 4) {                                                            \
        int tn = (t_ + 1) & 511;                                                \
        const short* ep = XG + (long)((tn * 8 + rb) * 32 + ug) * 1024 +         \
                          erow * 32 + eu;                                       \
        XB[0] = loadus_nw(ep); XB[1] = loadus_nw(ep + 256);                     \
        XB[2] = loadus_nw(ep + 512); XB[3] = loadus_nw(ep + 768);               \
        asm volatile("s_waitcnt vmcnt(4)" ::: "memory");                        \
      } else {                                                                  \
        asm volatile("s_waitcnt vmcnt(0)" ::: "memory");                        \
      }                                                                         \
      __builtin_amdgcn_sched_barrier(0);                                        \
      int kc_ = lane >> 1;                                                      \
      int wb = kc_ * 1024 + srow * 64 + (lane & 1) * 32;                        \
      int sw = hswz(srow, kc_);                                                 \
      *(u4*)(hA + (wb ^ sw)) = v0;                                              \
      *(u4*)(hA + ((wb + 16) ^ sw)) = v1;                                       \
    }                                                                           \
    __syncthreads(); /* S2: hA ready */                                         \
    f4 a0{0.f, 0.f, 0.f, 0.f}, a1{0.f, 0.f, 0.f, 0.f};                          \
    _Pragma("unroll")                                                           \
    for (int kc2 = 0; kc2 < 16; ++kc2) {                                        \
      int kci = kh * 16 + kc2;                                                  \
      int ad = (kci * 1024 + lr * 64 + lk * 16) ^ hswz(lr, kci);                \
      s8 ah = *(const s8*)(hA + ad);                                            \
      a0 = __builtin_amdgcn_mfma_f32_16x16x32_bf16(ah, wf[kc2], a0, 0, 0, 0);   \
      a1 = __builtin_amdgcn_mfma_f32_16x16x32_bf16(ah, wf[16 + kc2], a1, 0, 0, 0); \
    }                                                                           \
    if (lk < 2) {                                                               \
      _Pragma("unroll")                                                         \
      for (int j = 0; j < 4; ++j) {                                             \
        pre[kh][g][lk * 4 + j][lr] = a0[j];                                     \
        pre[kh][g][lk * 4 + j][16 + lr] = a1[j];                                \
      }                                                                         \
    }                                                                           \
    __syncthreads(); /* S3: pre ready */                                        \
    if (wid < 4) {                                                              \
      float pi = pre[0][0][erow][eu] + pre[1][0][erow][eu] + bf2fu(XA[0]);      \
      float pf = pre[0][1][erow][eu] + pre[1][1][erow][eu] + bf2fu(XA[1]);      \
      float po = pre[0][2][erow][eu] + pre[1][2][erow][eu] + bf2fu(XA[2]);      \
      float pc = pre[0][3][erow][eu] + pre[1][3][erow][eu] + bf2fu(XA[3]);      \
      float fi = sigm(pi), ff = sigm(pf), fo = sigm(po);                        \
      float ch = tanh_f(pc);                                                    \
      c = ff * c + fi * ch;                                                     \
      float h = fo * tanh_f(c);                                                 \
      short hh = f2bf(h);                                                       \
      short* p = &hbuf[((t_ + 1) & 1) * 65536 + (long)grow * 1024 + gu];        \
      *(volatile short*)p = hh;                                                 \
      if (esc_)                                                                 \
        __hip_atomic_store(p, hh, __ATOMIC_RELAXED, __HIP_MEMORY_SCOPE_AGENT);  \
      if ((t_ + 1) & 1) hP1 = hh; else hP0 = hh;                                \
      HS[(long)t_ * 65536 + (long)grow * 1024 + gu] = hh;                       \
      vm0_fence(); /* own h (+HS) stores ack'd */                               \
      if (lane == 0) {                                                          \
        unsigned int old = atomicAdd(&cnt, 1u);                                 \
        if (old == (unsigned)(4 * t_ + 7)) { /* 4th wave this step */           \
          *(volatile unsigned int*)myflag = (unsigned int)(t_ + 2);             \
          if (esc_)                                                             \
            __hip_atomic_store(myflag, (unsigned int)(t_ + 2),                  \
                               __ATOMIC_RELAXED, __HIP_MEMORY_SCOPE_AGENT);     \
        }                                                                       \
      }                                                                         \
    }                                                                           \
  }

  for (int t2 = 0; t2 < 512; t2 += 2) {
    LSTM_STEP(t2, xE, xO);
    LSTM_STEP(t2 + 1, xO, xE);
  }
#undef LSTM_STEP
}

// ---------------- launch ----------------
extern "C" void kernel_launch(void* const* d_in, const int* in_sizes, int n_in,
                              void* d_out, int out_size, void* d_ws, size_t ws_size,
                              hipStream_t stream) {
  const float* x = (const float*)d_in[0];
  const float* Wx[4] = {(const float*)d_in[1], (const float*)d_in[4], (const float*)d_in[7], (const float*)d_in[10]};
  const float* Wh[4] = {(const float*)d_in[2], (const float*)d_in[5], (const float*)d_in[8], (const float*)d_in[11]};
  const float* bg[4] = {(const float*)d_in[3], (const float*)d_in[6], (const float*)d_in[9], (const float*)d_in[12]};
  const float* Why = (const float*)d_in[13];
  const float* by  = (const float*)d_in[14];

  char* ws = (char*)d_ws;                     // layout (bytes):
  short* xbf  = (short*)(ws);                 // 67,108,864  x bf16 [512][64][1024]
  short* HS   = (short*)(ws);                 // reuses xbf (dead after big GEMM)
  short* Wxt  = (short*)(ws + 67108864);      //  8,388,608
  short* Wht  = (short*)(ws + 75497472);      //  8,388,608
  short* Whyt = (short*)(ws + 83886080);      //  2,097,152
  float* bcat = (float*)(ws + 85983232);      //     16,384
  short* XG   = (short*)(ws + 85999616);      // 268,435,456 [512][8][32][4][8][32]
  short* hbuf = (short*)(ws + 354435072);     //    262,144  [2][64][1024] bf16
  unsigned int* flags = (unsigned int*)(ws + 354697216);  // 16,384

  hipLaunchKernelGGL(k_x_relayout, dim3(16384), dim3(256), 0, stream, x, xbf);
  for (int gi = 0; gi < 4; ++gi) {
    hipLaunchKernelGGL(k_transpose_c, dim3(32, 32), dim3(256), 0, stream, Wx[gi], Wxt + (long)gi * 1048576);
    hipLaunchKernelGGL(k_transpose_c, dim3(32, 32), dim3(256), 0, stream, Wh[gi], Wht + (long)gi * 1048576);
  }
  hipLaunchKernelGGL(k_transpose_c, dim3(32, 32), dim3(256), 0, stream, Why, Whyt);
  hipLaunchKernelGGL(k_bcat, dim3(16), dim3(256), 0, stream, bg[0], bg[1], bg[2], bg[3], bcat);

  hipLaunchKernelGGL((k_gemm_bt<short, 2>), dim3(32, 256), dim3(256), 0, stream,
                     xbf, Wxt, bcat, XG, 32768, 4096, 1024);

  hipMemsetAsync(flags, 0, 16384, stream);

  {
    void* args[] = { (void*)&XG, (void*)&Wht, (void*)&hbuf, (void*)&flags, (void*)&HS };
    hipLaunchCooperativeKernel((void*)k_lstm_p, dim3(256), dim3(512), args, 0, stream);
  }

  hipLaunchKernelGGL((k_gemm_bt<float, 1>), dim3(8, 256), dim3(256), 0, stream,
                     HS, Whyt, by, (float*)d_out, 32768, 1024, 1024);
}

// Round 12
// 2185.194 us; speedup vs baseline: 2.0566x; 1.3767x over previous
//
#include <hip/hip_runtime.h>
#include <hip/hip_bf16.h>

typedef __attribute__((ext_vector_type(8))) short s8;
typedef __attribute__((ext_vector_type(4))) float f4;
typedef __attribute__((ext_vector_type(4))) unsigned int u4;

#define DEVI static __device__ __forceinline__

DEVI float bf2f(short u) {
  union { float f; unsigned int i; } v;
  v.i = ((unsigned int)(unsigned short)u) << 16;
  return v.f;
}
DEVI float bf2fu(unsigned int u) {
  union { float f; unsigned int i; } v;
  v.i = u << 16;
  return v.f;
}
DEVI short f2bf(float f) {
  union { float f; unsigned int i; } v; v.f = f;
  unsigned int r = v.i + 0x7fffu + ((v.i >> 16) & 1u);
  return (short)(r >> 16);
}
DEVI void gload_lds16(const void* g, void* l) {
  __builtin_amdgcn_global_load_lds(
      (const __attribute__((address_space(1))) unsigned int*)g,
      (__attribute__((address_space(3))) unsigned int*)l, 16, 0, 0);
}
DEVI float sigm(float x) { return 1.f / (1.f + __expf(-x)); }
// fast tanh: 1 - 2/(e^2x + 1); saturates to +-1 cleanly (exp -> inf or 0)
DEVI float tanh_f(float x) { return 1.f - 2.f / (__expf(2.f * x) + 1.f); }

// sc0: bypass L1, serviced by the XCD's L2
DEVI u4 load4_sc0(const void* p) {
  u4 v;
  asm volatile("global_load_dwordx4 %0, %1, off sc0" : "=v"(v) : "v"(p) : "memory");
  return v;
}
// sc0 sc1: bypass L1+L2, serviced by IF$ (cross-XCD-safe)
DEVI u4 load4_sc01(const void* p) {
  u4 v;
  asm volatile("global_load_dwordx4 %0, %1, off sc0 sc1" : "=v"(v) : "v"(p) : "memory");
  return v;
}
DEVI unsigned int loadw_sc0(const unsigned int* p) {
  unsigned int v;
  asm volatile("global_load_dword %0, %1, off sc0" : "=v"(v) : "v"(p) : "memory");
  asm volatile("s_waitcnt vmcnt(0)" ::: "memory");
  return v;
}
DEVI unsigned int loadw_sc01(const unsigned int* p) {
  unsigned int v;
  asm volatile("global_load_dword %0, %1, off sc0 sc1" : "=v"(v) : "v"(p) : "memory");
  asm volatile("s_waitcnt vmcnt(0)" ::: "memory");
  return v;
}
// ushort load, no wait (for the counted-vmcnt region)
DEVI unsigned int loadus_nw(const void* p) {
  unsigned int v;
  asm volatile("global_load_ushort %0, %1, off" : "=v"(v) : "v"(p) : "memory");
  return v;
}
DEVI void vm0_fence() {
  asm volatile("s_waitcnt vmcnt(0)" ::: "memory");
  __builtin_amdgcn_sched_barrier(0);
}

// LDS swizzle for hA [32 kc][16 row][64B]: XOR bits 4-5 with f(row>>1, kc).
// Bijective (mask independent of XORed bits); spreads lr and lr+4 across quads.
DEVI int hswz(int row, int kc) { return (((row >> 1) + kc) & 3) << 4; }

// ---------------- converts ----------------
// x [64][512][1024] f32  ->  xbf [512][64][1024] bf16 (t-major rows)
__global__ void k_x_relayout(const float* __restrict__ in, short* __restrict__ out) {
  long idx8 = (long)blockIdx.x * blockDim.x + threadIdx.x;
  long E = idx8 * 8;
  long row = E >> 10;
  long col = E & 1023;
  long t = row >> 6, b = row & 63;
  const float* src = in + ((b << 9) + t) * 1024 + col;
  float4 a = *(const float4*)(src);
  float4 c = *(const float4*)(src + 4);
  s8 o;
  o[0] = f2bf(a.x); o[1] = f2bf(a.y); o[2] = f2bf(a.z); o[3] = f2bf(a.w);
  o[4] = f2bf(c.x); o[5] = f2bf(c.y); o[6] = f2bf(c.z); o[7] = f2bf(c.w);
  *(s8*)(out + E) = o;
}

// src [1024][1024] f32 row-major [k][n]  ->  dst [1024][1024] bf16 at [n][k]
__global__ void k_transpose_c(const float* __restrict__ src, short* __restrict__ dst) {
  __shared__ float tile[32][33];
  int n0 = blockIdx.x * 32, k0 = blockIdx.y * 32;
  int lx = threadIdx.x & 31, ly = threadIdx.x >> 5;
#pragma unroll
  for (int r = 0; r < 32; r += 8)
    tile[ly + r][lx] = src[(long)(k0 + ly + r) * 1024 + n0 + lx];
  __syncthreads();
#pragma unroll
  for (int r = 0; r < 32; r += 8)
    dst[(long)(n0 + ly + r) * 1024 + k0 + lx] = f2bf(tile[lx][ly + r]);
}

__global__ void k_bcat(const float* __restrict__ b0, const float* __restrict__ b1,
                       const float* __restrict__ b2, const float* __restrict__ b3,
                       float* __restrict__ o) {
  int i = blockIdx.x * 256 + threadIdx.x;
  int j = i & 1023;
  float v;
  switch (i >> 10) { case 0: v = b0[j]; break; case 1: v = b1[j]; break;
                     case 2: v = b2[j]; break; default: v = b3[j]; }
  o[i] = v;
}

// ---------------- bf16 GEMM: C[M][N] = A[M][K] @ Bt[N][K]^T + bias ----------------
// REMAP 0: linear. 1: row (t*64+b) -> (b*512+t).
// REMAP 2: XG permute [t][rb8][ug32][g4][row8][u32] for the recurrence kernel.
template <typename OutT, int REMAP>
__global__ __launch_bounds__(256) void k_gemm_bt(
    const short* __restrict__ A, const short* __restrict__ Bt,
    const float* __restrict__ bias, OutT* __restrict__ C,
    int M, int N, int K) {
  __shared__ __align__(16) char As[8192];
  __shared__ __align__(16) char Bs[8192];
  const int tid = threadIdx.x;
  const int wid = tid >> 6, lane = tid & 63;
  const int lr = lane & 15, lk = lane >> 4;
  const int wy = wid >> 1, wx = wid & 1;
  const long bm = (long)blockIdx.y * 128, bn = (long)blockIdx.x * 128;
  const char* Ab = (const char*)A;
  const char* Bb = (const char*)Bt;
  f4 acc[4][4];
#pragma unroll
  for (int i = 0; i < 4; ++i)
#pragma unroll
    for (int j = 0; j < 4; ++j) acc[i][j] = f4{0.f, 0.f, 0.f, 0.f};

  for (int k0 = 0; k0 < K; k0 += 32) {
#pragma unroll
    for (int p = 0; p < 2; ++p) {
      int off = p * 4096 + tid * 16;
      int r = off >> 6, cb = off & 63;
      int sw = cb ^ ((r & 3) << 4);
      gload_lds16(Ab + ((bm + r) * K + k0) * 2 + sw, As + p * 4096 + wid * 1024);
      gload_lds16(Bb + ((bn + r) * K + k0) * 2 + sw, Bs + p * 4096 + wid * 1024);
    }
    __syncthreads();
    s8 af[4], bfr[4];
#pragma unroll
    for (int mi = 0; mi < 4; ++mi) {
      int r = wy * 64 + mi * 16 + lr;
      int x = r * 64 + lk * 16;
      af[mi] = *(const s8*)(As + (x ^ ((r & 3) << 4)));
    }
#pragma unroll
    for (int ni = 0; ni < 4; ++ni) {
      int r = wx * 64 + ni * 16 + lr;
      int x = r * 64 + lk * 16;
      bfr[ni] = *(const s8*)(Bs + (x ^ ((r & 3) << 4)));
    }
#pragma unroll
    for (int mi = 0; mi < 4; ++mi)
#pragma unroll
      for (int ni = 0; ni < 4; ++ni)
        acc[mi][ni] = __builtin_amdgcn_mfma_f32_16x16x32_bf16(af[mi], bfr[ni], acc[mi][ni], 0, 0, 0);
    __syncthreads();
  }
#pragma unroll
  for (int mi = 0; mi < 4; ++mi)
#pragma unroll
    for (int ni = 0; ni < 4; ++ni)
#pragma unroll
      for (int j = 0; j < 4; ++j) {
        long row = bm + wy * 64 + mi * 16 + lk * 4 + j;
        long col = bn + wx * 64 + ni * 16 + lr;
        float v = acc[mi][ni][j] + bias[col];
        long off;
        if constexpr (REMAP == 1) {
          off = ((row & 63) * 512 + (row >> 6)) * (long)N + col;
        } else if constexpr (REMAP == 2) {
          long tt = row >> 6, b = row & 63;
          long gg = col >> 10, u = col & 1023;
          off = (((((tt << 3) + (b >> 3)) << 5) + (u >> 5)) * 4 + gg) * 256 +
                ((b & 7) << 5) + (u & 31);
        } else {
          off = row * (long)N + col;
        }
        if constexpr (sizeof(OutT) == 2) C[off] = f2bf(v);
        else                              C[off] = v;
      }
}

// ---------------- persistent LSTM recurrence (R9 protocol + counted vmcnt) ------
// 256 WGs x 512 threads, 1 WG/CU. WG = (rb = wg&7: 8 batch rows) x (ug = wg>>3: 32 units).
// FAST PATH (wg%8 == XCD round-robin): producers publish h + flag with PLAIN
// write-back stores (ack at local L2); consumers poll/bulk-load with sc0 (same L2).
// RECOVERY (any other mapping): poll timeout -> whole-WG sticky escalation:
// republish BOTH retained h parities (hP0/hP1; max inter-WG skew is 1 step) +
// own flag at agent scope (IF$); poll/bulk switch to sc0+sc1. Self-healing.
// R12 changes vs R9: (1) staging uses COUNTED vmcnt(4) so the XG (HBM) prefetch
// drains at the publish fence (hidden under MFMA+elementwise) instead of before
// the LDS write; (2) fast tanh in the elementwise phase.
__global__ __launch_bounds__(512, 2) void k_lstm_p(
    const short* __restrict__ XG,     // [512][8][32][4][8][32] permuted, bias folded
    const short* __restrict__ Wht,    // [4096][1024]
    short* __restrict__ hbuf,         // [2][64][1024] bf16
    unsigned int* __restrict__ flags, // [256] monotonic, spaced 16 u32 (64 B)
    short* __restrict__ HS) {         // [512][64][1024] bf16
  __shared__ __align__(16) char hA[32768];   // [32 kc][16 row][64B], swz = hswz()
  __shared__ float pre[2][4][8][33];          // [kh][gate][row][unit]
  __shared__ int eflag;                       // sticky: 1 => escalated (IF$ mode)
  __shared__ int pollok;                      // monotonic: last confirmed target

  const int tid = threadIdx.x;
  const int wg = blockIdx.x;
  const int wid = tid >> 6, lane = tid & 63;
  const int lr = lane & 15, lk = lane >> 4;
  const int g = wid & 3, kh = wid >> 2;
  const int rb = wg & 7, ug = wg >> 3;

  if (tid == 0) { eflag = 0; pollok = 0; }

  // recurrent-weight B-fragments: [nt(2)][kc(16)] = 32 x s8 (unified VGPR/AGPR file)
  s8 wf[32];
  {
    const short* wbase = Wht + (long)(g * 1024 + ug * 32 + lr) * 1024 + kh * 512 + lk * 8;
#pragma unroll
    for (int nt = 0; nt < 2; ++nt)
#pragma unroll
      for (int kc = 0; kc < 16; ++kc)
        wf[nt * 16 + kc] = *(const s8*)(wbase + nt * 16384 + kc * 32);
  }
#pragma unroll
  for (int i = 0; i < 32; ++i) asm volatile("" : "+v"(wf[i]));

  const int srow = tid >> 6;              // staging row 0..7 (= wave id)
  // zero pad rows 8..15 of hA once (MFMA M=16, only 8 real rows)
  {
    int zr = 8 + srow;
    int kc = lane >> 1;
    int base = kc * 1024 + zr * 64 + (lane & 1) * 32;
    int sw = hswz(zr, kc);
    *(u4*)(hA + (base ^ sw)) = u4{0, 0, 0, 0};
    *(u4*)(hA + ((base + 16) ^ sw)) = u4{0, 0, 0, 0};
  }

  const int erow = tid >> 5, eu = tid & 31;      // elementwise ids (tid<256)
  const int grow = rb * 8 + (erow & 7);
  const int gu = ug * 32 + eu;
  float c = 0.f;
  short hP0 = 0, hP1 = 0;   // last published h per parity (recovery republish)

  // h0 = 0 (parity-0, plain) + publish flag=1 (plain + agent once, cheap)
  if (tid < 256) {
    short* p = &hbuf[(long)grow * 1024 + gu];
    *(volatile short*)p = 0;
  }
  vm0_fence();
  __syncthreads();
  if (tid == 0) {
    unsigned int* f = &flags[(unsigned)((rb << 5) + ug) << 4];
    *(volatile unsigned int*)f = 1u;
    __hip_atomic_store(f, 1u, __ATOMIC_RELAXED, __HIP_MEMORY_SCOPE_AGENT);
  }

  // XG prefetch for t=0 (elementwise threads only; 4 gate values each)
  unsigned int xA0 = 0, xA1 = 0, xA2 = 0, xA3 = 0, xB0, xB1, xB2, xB3;
  if (tid < 256) {
    const short* ep = XG + (long)((0 * 8 + rb) * 32 + ug) * 1024 + erow * 32 + eu;
    xA0 = (unsigned short)ep[0];   xA1 = (unsigned short)ep[256];
    xA2 = (unsigned short)ep[512]; xA3 = (unsigned short)ep[768];
  }

  for (int t = 0; t < 512; ++t) {
    const int target = t + 1;

    // ---- S0/S1: flag poll with bounded recovery loop ----
    int safety = 0;
    while (true) {
      if (wid == 0) {
        int ok = 1;
        if (lane < 32) {
          const unsigned int* f = &flags[(unsigned)((rb << 5) + lane) << 4];
          int esc = eflag;
          ok = 0;
          for (int r = 0; r < 256; ++r) {
            unsigned int v = esc ? loadw_sc01(f) : loadw_sc0(f);
            if (v >= (unsigned int)target) { ok = 1; break; }
          }
        }
        unsigned long long m = __ballot(ok);
        if (lane == 0 && m == ~0ull) pollok = target;
      }
      __syncthreads();
      if (pollok >= target) break;
      if (++safety > 4096) break;  // fail visibly (validation) rather than hang
      // recovery: sticky escalate; republish both h parities + own flag at IF$
      if (tid == 0) eflag = 1;
      if (tid < 256) {
        __hip_atomic_store(&hbuf[(long)grow * 1024 + gu], hP0,
                           __ATOMIC_RELAXED, __HIP_MEMORY_SCOPE_AGENT);
        __hip_atomic_store(&hbuf[65536 + (long)grow * 1024 + gu], hP1,
                           __ATOMIC_RELAXED, __HIP_MEMORY_SCOPE_AGENT);
      }
      vm0_fence();
      __syncthreads();
      if (tid == 0) {
        unsigned int* f = &flags[(unsigned)((rb << 5) + ug) << 4];
        *(volatile unsigned int*)f = (unsigned int)target;
        __hip_atomic_store(f, (unsigned int)target,
                           __ATOMIC_RELAXED, __HIP_MEMORY_SCOPE_AGENT);
      }
    }
    const int esc = eflag;

    // ---- bulk-stage h rows [rb*8,+8): 2 x dwordx4 per thread, ONCE ----
    // Counted vmcnt: h loads issued FIRST (oldest), XG prefetch after; wait
    // vmcnt(4) passes once the two h L2-loads land. XG drains at the publish
    // fence, hidden under MFMA + elementwise (~900 cy).
    {
      const char* rowp = (const char*)(hbuf + (t & 1) * 65536 +
                                       (long)(rb * 8 + srow) * 1024) + lane * 32;
      u4 v0, v1;
      if (esc) { v0 = load4_sc01(rowp); v1 = load4_sc01(rowp + 16); }
      else     { v0 = load4_sc0(rowp);  v1 = load4_sc0(rowp + 16); }
      if (tid < 256) {
        const short* ep = XG + (long)((((t + 1) & 511) * 8 + rb) * 32 + ug) * 1024 + erow * 32 + eu;
        xB0 = loadus_nw(ep);       xB1 = loadus_nw(ep + 256);
        xB2 = loadus_nw(ep + 512); xB3 = loadus_nw(ep + 768);
        asm volatile("s_waitcnt vmcnt(4)" ::: "memory");
      } else {
        asm volatile("s_waitcnt vmcnt(0)" ::: "memory");
      }
      __builtin_amdgcn_sched_barrier(0);
      int kc = lane >> 1;
      int wb = kc * 1024 + srow * 64 + (lane & 1) * 32;
      int sw = hswz(srow, kc);
      *(u4*)(hA + (wb ^ sw)) = v0;
      *(u4*)(hA + ((wb + 16) ^ sw)) = v1;
    }
    __syncthreads();  // S2: hA ready

    // ---- MFMA: 16 A-reads, 32 MFMA per wave (2 independent 16-chains) ----
    f4 a0{0.f, 0.f, 0.f, 0.f}, a1{0.f, 0.f, 0.f, 0.f};
#pragma unroll
    for (int kc2 = 0; kc2 < 16; ++kc2) {
      int kci = kh * 16 + kc2;
      int ad = (kci * 1024 + lr * 64 + lk * 16) ^ hswz(lr, kci);
      s8 ah = *(const s8*)(hA + ad);
      a0 = __builtin_amdgcn_mfma_f32_16x16x32_bf16(ah, wf[kc2], a0, 0, 0, 0);
      a1 = __builtin_amdgcn_mfma_f32_16x16x32_bf16(ah, wf[16 + kc2], a1, 0, 0, 0);
    }

    // ---- gate-partial exchange (C/D: col=lr, row=lk*4+j; keep rows 0-7) ----
    if (lk < 2) {
#pragma unroll
      for (int j = 0; j < 4; ++j) {
        pre[kh][g][lk * 4 + j][lr] = a0[j];
        pre[kh][g][lk * 4 + j][16 + lr] = a1[j];
      }
    }
    __syncthreads();  // S3: pre ready

    // ---- elementwise state update + h publish (plain; dual only if escalated) ----
    if (tid < 256) {
      float pi = pre[0][0][erow][eu] + pre[1][0][erow][eu] + bf2fu(xA0);
      float pf = pre[0][1][erow][eu] + pre[1][1][erow][eu] + bf2fu(xA1);
      float po = pre[0][2][erow][eu] + pre[1][2][erow][eu] + bf2fu(xA2);
      float pc = pre[0][3][erow][eu] + pre[1][3][erow][eu] + bf2fu(xA3);
      float fi = sigm(pi), ff = sigm(pf), fo = sigm(po);
      float ch = tanh_f(pc);
      c = ff * c + fi * ch;
      float h = fo * tanh_f(c);
      short hh = f2bf(h);
      short* p = &hbuf[((t + 1) & 1) * 65536 + (long)grow * 1024 + gu];
      *(volatile short*)p = hh;                                          // local L2
      if (esc)
        __hip_atomic_store(p, hh, __ATOMIC_RELAXED, __HIP_MEMORY_SCOPE_AGENT);
      if ((t + 1) & 1) hP1 = hh; else hP0 = hh;
      HS[(long)t * 65536 + (long)grow * 1024 + gu] = hh;
      xA0 = xB0; xA1 = xB1; xA2 = xB2; xA3 = xB3;
    }
    vm0_fence();       // h stores ack'd at L2; XG prefetch drains here (hidden)
    __syncthreads();   // S4: whole WG's publish complete
    if (tid == 0) {
      unsigned int* f = &flags[(unsigned)((rb << 5) + ug) << 4];
      unsigned int fv = (unsigned int)(t + 2);
      *(volatile unsigned int*)f = fv;                                   // local L2
      if (esc)
        __hip_atomic_store(f, fv, __ATOMIC_RELAXED, __HIP_MEMORY_SCOPE_AGENT);
    }
  }
}

// ---------------- launch ----------------
extern "C" void kernel_launch(void* const* d_in, const int* in_sizes, int n_in,
                              void* d_out, int out_size, void* d_ws, size_t ws_size,
                              hipStream_t stream) {
  const float* x = (const float*)d_in[0];
  const float* Wx[4] = {(const float*)d_in[1], (const float*)d_in[4], (const float*)d_in[7], (const float*)d_in[10]};
  const float* Wh[4] = {(const float*)d_in[2], (const float*)d_in[5], (const float*)d_in[8], (const float*)d_in[11]};
  const float* bg[4] = {(const float*)d_in[3], (const float*)d_in[6], (const float*)d_in[9], (const float*)d_in[12]};
  const float* Why = (const float*)d_in[13];
  const float* by  = (const float*)d_in[14];

  char* ws = (char*)d_ws;                     // layout (bytes):
  short* xbf  = (short*)(ws);                 // 67,108,864  x bf16 [512][64][1024]
  short* HS   = (short*)(ws);                 // reuses xbf (dead after big GEMM)
  short* Wxt  = (short*)(ws + 67108864);      //  8,388,608
  short* Wht  = (short*)(ws + 75497472);      //  8,388,608
  short* Whyt = (short*)(ws + 83886080);      //  2,097,152
  float* bcat = (float*)(ws + 85983232);      //     16,384
  short* XG   = (short*)(ws + 85999616);      // 268,435,456 [512][8][32][4][8][32]
  short* hbuf = (short*)(ws + 354435072);     //    262,144  [2][64][1024] bf16
  unsigned int* flags = (unsigned int*)(ws + 354697216);  // 16,384

  hipLaunchKernelGGL(k_x_relayout, dim3(16384), dim3(256), 0, stream, x, xbf);
  for (int gi = 0; gi < 4; ++gi) {
    hipLaunchKernelGGL(k_transpose_c, dim3(32, 32), dim3(256), 0, stream, Wx[gi], Wxt + (long)gi * 1048576);
    hipLaunchKernelGGL(k_transpose_c, dim3(32, 32), dim3(256), 0, stream, Wh[gi], Wht + (long)gi * 1048576);
  }
  hipLaunchKernelGGL(k_transpose_c, dim3(32, 32), dim3(256), 0, stream, Why, Whyt);
  hipLaunchKernelGGL(k_bcat, dim3(16), dim3(256), 0, stream, bg[0], bg[1], bg[2], bg[3], bcat);

  hipLaunchKernelGGL((k_gemm_bt<short, 2>), dim3(32, 256), dim3(256), 0, stream,
                     xbf, Wxt, bcat, XG, 32768, 4096, 1024);

  hipMemsetAsync(flags, 0, 16384, stream);

  {
    void* args[] = { (void*)&XG, (void*)&Wht, (void*)&hbuf, (void*)&flags, (void*)&HS };
    hipLaunchCooperativeKernel((void*)k_lstm_p, dim3(256), dim3(512), args, 0, stream);
  }

  hipLaunchKernelGGL((k_gemm_bt<float, 1>), dim3(8, 256), dim3(256), 0, stream,
                     HS, Whyt, by, (float*)d_out, 32768, 1024, 1024);
}